// Round 1
// baseline (1186.123 us; speedup 1.0000x reference)
//
#include <hip/hip_runtime.h>

#define NNODES 50000
#define NEDGES 1600000
#define IN_CH 256
#define HEADS 4
#define OUT_CH 32
#define HC 128  // HEADS*OUT_CH

typedef unsigned int u32;
typedef unsigned short u16;

__device__ __forceinline__ float b2f(u16 s) { return __uint_as_float(((u32)s) << 16); }
__device__ __forceinline__ u16 f2b(float f) {
  u32 u = __float_as_uint(f);
  u32 r = (u + 0x7FFFu + ((u >> 16) & 1u)) >> 16;
  return (u16)r;
}
// monotone float -> uint map for atomicMax-based float max
__device__ __forceinline__ u32 fmap(float f) {
  u32 u = __float_as_uint(f);
  return (u & 0x80000000u) ? ~u : (u | 0x80000000u);
}
__device__ __forceinline__ float funmap(u32 m) {
  u32 u = (m & 0x80000000u) ? (m & 0x7FFFFFFFu) : ~m;
  return __uint_as_float(u);
}

// ---- K1: h = x @ W  (50000x256 @ 256x128), store f32 + bf16 copies ----
__global__ __launch_bounds__(256) void k_gemm(const float* __restrict__ x,
                                              const float* __restrict__ W,
                                              float* __restrict__ hf,
                                              u16* __restrict__ hb) {
  __shared__ float xsT[32][64];   // [k][row]
  __shared__ float Ws[32][128];   // [k][col]
  const int tid = threadIdx.x;
  const int row0 = blockIdx.x * 64;
  const int tc = tid & 31;   // col group: cols tc*4..+3
  const int tr = tid >> 5;   // row group: rows tr*8..+7
  float4 acc[8];
#pragma unroll
  for (int i = 0; i < 8; ++i) acc[i] = make_float4(0.f, 0.f, 0.f, 0.f);

  for (int kt = 0; kt < IN_CH; kt += 32) {
    // x tile 64x32 -> transposed LDS
#pragma unroll
    for (int li = 0; li < 2; ++li) {
      int f4i = tid + li * 256;          // 0..511
      int r = f4i >> 3;
      int kc = (f4i & 7) << 2;
      int grow = row0 + r;
      float4 v = make_float4(0.f, 0.f, 0.f, 0.f);
      if (grow < NNODES) v = *(const float4*)&x[(size_t)grow * IN_CH + kt + kc];
      xsT[kc + 0][r] = v.x;
      xsT[kc + 1][r] = v.y;
      xsT[kc + 2][r] = v.z;
      xsT[kc + 3][r] = v.w;
    }
    // W tile 32x128
#pragma unroll
    for (int li = 0; li < 4; ++li) {
      int f4i = tid + li * 256;          // 0..1023
      int kk = f4i >> 5;
      int c4 = (f4i & 31) << 2;
      *(float4*)&Ws[kk][c4] = *(const float4*)&W[(size_t)(kt + kk) * HC + c4];
    }
    __syncthreads();
#pragma unroll 4
    for (int kk = 0; kk < 32; ++kk) {
      float4 b = *(const float4*)&Ws[kk][tc << 2];
      float4 a0 = *(const float4*)&xsT[kk][tr << 3];
      float4 a1 = *(const float4*)&xsT[kk][(tr << 3) + 4];
      float av[8] = {a0.x, a0.y, a0.z, a0.w, a1.x, a1.y, a1.z, a1.w};
#pragma unroll
      for (int i = 0; i < 8; ++i) {
        acc[i].x += av[i] * b.x;
        acc[i].y += av[i] * b.y;
        acc[i].z += av[i] * b.z;
        acc[i].w += av[i] * b.w;
      }
    }
    __syncthreads();
  }
#pragma unroll
  for (int i = 0; i < 8; ++i) {
    int grow = row0 + (tr << 3) + i;
    if (grow < NNODES) {
      *(float4*)&hf[(size_t)grow * HC + (tc << 2)] = acc[i];
      u16 q[4] = {f2b(acc[i].x), f2b(acc[i].y), f2b(acc[i].z), f2b(acc[i].w)};
      *(ushort4*)&hb[(size_t)grow * HC + (tc << 2)] = *(ushort4*)q;
    }
  }
}

// ---- K2: s_src[n][h] = h[n,h,:].a_src[h]; s_dst likewise (fp32 h) ----
__global__ __launch_bounds__(256) void k_scores(const float* __restrict__ hf,
                                                const float* __restrict__ attn,
                                                float* __restrict__ s_src,
                                                float* __restrict__ s_dst) {
  int idx = blockIdx.x * 256 + threadIdx.x;
  if (idx >= NNODES * HEADS) return;
  int n = idx >> 2, hd = idx & 3;
  const float* hrow = hf + (size_t)n * HC + hd * OUT_CH;
  const float* arow = attn + hd * 64;
  float ss = 0.f, sd = 0.f;
#pragma unroll
  for (int c = 0; c < OUT_CH; ++c) {
    float hv = hrow[c];
    ss += hv * arow[c];
    sd += hv * arow[32 + c];
  }
  s_src[idx] = ss;
  s_dst[idx] = sd;
}

// ---- K3: degree histogram ----
__global__ void k_hist(const int* __restrict__ rowi, int* __restrict__ counts) {
  int e = blockIdx.x * 256 + threadIdx.x;
  if (e < NEDGES) atomicAdd(&counts[rowi[e]], 1);
}

// ---- K4: exclusive prefix sum (single block) ----
__global__ __launch_bounds__(1024) void k_scan(const int* __restrict__ counts,
                                               int* __restrict__ row_ptr) {
  __shared__ int sums[1024];
  const int t = threadIdx.x;
  const int CH = (NNODES + 1023) / 1024;  // 49
  int base = t * CH;
  int s = 0;
  for (int i = 0; i < CH; ++i) {
    int idx = base + i;
    if (idx < NNODES) s += counts[idx];
  }
  sums[t] = s;
  __syncthreads();
  for (int off = 1; off < 1024; off <<= 1) {
    int v = (t >= off) ? sums[t - off] : 0;
    __syncthreads();
    sums[t] += v;
    __syncthreads();
  }
  int run = (t == 0) ? 0 : sums[t - 1];
  for (int i = 0; i < CH; ++i) {
    int idx = base + i;
    if (idx < NNODES) {
      row_ptr[idx] = run;
      run += counts[idx];
    }
  }
  if (t == 1023) row_ptr[NNODES] = run;
}

// ---- K5: scatter edge ids into CSR buckets ----
__global__ void k_scatter(const int* __restrict__ rowi, const int* __restrict__ row_ptr,
                          int* __restrict__ cursor, int* __restrict__ edge_list) {
  int e = blockIdx.x * 256 + threadIdx.x;
  if (e < NEDGES) {
    int r = rowi[e];
    int pos = row_ptr[r] + atomicAdd(&cursor[r], 1);
    edge_list[pos] = e;
  }
}

// ---- K6: alpha = leaky_relu(s_src[row]+s_dst[col]); seg-max via mapped atomicMax ----
__global__ void k_alpha(const int* __restrict__ rowi, const int* __restrict__ coli,
                        const float* __restrict__ s_src, const float* __restrict__ s_dst,
                        float* __restrict__ alpha_out, u32* __restrict__ segmax) {
  int e = blockIdx.x * 256 + threadIdx.x;
  if (e >= NEDGES) return;
  int r = rowi[e], c = coli[e];
  float4 a = *(const float4*)&s_src[(size_t)r * 4];
  float4 b = *(const float4*)&s_dst[(size_t)c * 4];
  float4 al;
  al.x = a.x + b.x; al.x = al.x >= 0.f ? al.x : 0.2f * al.x;
  al.y = a.y + b.y; al.y = al.y >= 0.f ? al.y : 0.2f * al.y;
  al.z = a.z + b.z; al.z = al.z >= 0.f ? al.z : 0.2f * al.z;
  al.w = a.w + b.w; al.w = al.w >= 0.f ? al.w : 0.2f * al.w;
  *(float4*)&alpha_out[(size_t)e * 4] = al;
  u32* sm = segmax + (size_t)r * 4;
  atomicMax(&sm[0], fmap(al.x));
  atomicMax(&sm[1], fmap(al.y));
  atomicMax(&sm[2], fmap(al.z));
  atomicMax(&sm[3], fmap(al.w));
}

// ---- K7: ex = exp(alpha - segmax[row]); denom += ex (in-place on alpha buffer) ----
__global__ void k_ex(const int* __restrict__ rowi, float* __restrict__ alpha_out,
                     const u32* __restrict__ segmax, float* __restrict__ denom) {
  int e = blockIdx.x * 256 + threadIdx.x;
  if (e >= NEDGES) return;
  int r = rowi[e];
  float4 al = *(const float4*)&alpha_out[(size_t)e * 4];
  const u32* sm = segmax + (size_t)r * 4;
  float4 ex;
  ex.x = expf(al.x - funmap(sm[0]));
  ex.y = expf(al.y - funmap(sm[1]));
  ex.z = expf(al.z - funmap(sm[2]));
  ex.w = expf(al.w - funmap(sm[3]));
  *(float4*)&alpha_out[(size_t)e * 4] = ex;
  float* dn = denom + (size_t)r * 4;
  atomicAdd(&dn[0], ex.x);
  atomicAdd(&dn[1], ex.y);
  atomicAdd(&dn[2], ex.z);
  atomicAdd(&dn[3], ex.w);
}

// ---- K8: per-node wave: normalize alpha (write out), gather h[col] (bf16), accumulate, mean heads ----
__global__ __launch_bounds__(256) void k_aggr(const int* __restrict__ coli,
                                              const int* __restrict__ row_ptr,
                                              const int* __restrict__ edge_list,
                                              const float* __restrict__ denom,
                                              const u16* __restrict__ hb,
                                              float* __restrict__ alpha_out,
                                              float* __restrict__ out_mean) {
  const int wid = threadIdx.x >> 6;
  const int lane = threadIdx.x & 63;
  const int r = blockIdx.x * 4 + wid;
  if (r >= NNODES) return;
  const int p0 = row_ptr[r], p1 = row_ptr[r + 1];
  float4 dn = *(const float4*)&denom[(size_t)r * 4];
  float4 ri;
  ri.x = dn.x > 0.f ? 1.f / dn.x : 0.f;
  ri.y = dn.y > 0.f ? 1.f / dn.y : 0.f;
  ri.z = dn.z > 0.f ? 1.f / dn.z : 0.f;
  ri.w = dn.w > 0.f ? 1.f / dn.w : 0.f;
  const int hd = lane >> 4;
  float acc0 = 0.f, acc1 = 0.f;

  int e = 0, c = 0;
  if (p0 < p1) {
    e = edge_list[p0];
    c = coli[e];
  }
  for (int p = p0; p < p1; ++p) {
    int en = 0, cn = 0;
    if (p + 1 < p1) {
      en = edge_list[p + 1];
      cn = coli[en];
    }
    float4 ex4 = *(const float4*)&alpha_out[(size_t)e * 4];
    float4 an;
    an.x = ex4.x * ri.x;
    an.y = ex4.y * ri.y;
    an.z = ex4.z * ri.z;
    an.w = ex4.w * ri.w;
    if (lane == 0) *(float4*)&alpha_out[(size_t)e * 4] = an;
    float w = (hd == 0) ? an.x : (hd == 1) ? an.y : (hd == 2) ? an.z : an.w;
    u32 hv = *(const u32*)&hb[(size_t)c * HC + (lane << 1)];
    acc0 += w * b2f((u16)(hv & 0xFFFFu));
    acc1 += w * b2f((u16)(hv >> 16));
    e = en;
    c = cn;
  }
  // sum over the 4 head groups (lanes l, l^16, l^32, l^48), then mean
  acc0 += __shfl_xor(acc0, 16);
  acc0 += __shfl_xor(acc0, 32);
  acc1 += __shfl_xor(acc1, 16);
  acc1 += __shfl_xor(acc1, 32);
  if (lane < 16) {
    float2 o = make_float2(acc0 * 0.25f, acc1 * 0.25f);
    *(float2*)&out_mean[(size_t)r * 32 + (lane << 1)] = o;
  }
}

extern "C" void kernel_launch(void* const* d_in, const int* in_sizes, int n_in,
                              void* d_out, int out_size, void* d_ws, size_t ws_size,
                              hipStream_t stream) {
  const float* x = (const float*)d_in[0];
  const int* ei = (const int*)d_in[1];
  const float* W = (const float*)d_in[2];
  const float* attn = (const float*)d_in[3];
  const int* rowi = ei;
  const int* coli = ei + NEDGES;

  float* out_mean = (float*)d_out;
  float* alpha_out = (float*)d_out + (size_t)NNODES * 32;

  char* w = (char*)d_ws;
  u16* hb = (u16*)w;        w += (size_t)NNODES * HC * 2;      // 12.8 MB
  float* hf = (float*)w;    w += (size_t)NNODES * HC * 4;      // 25.6 MB
  float* s_src = (float*)w; w += (size_t)NNODES * 4 * 4;
  float* s_dst = (float*)w; w += (size_t)NNODES * 4 * 4;
  u32* segmax = (u32*)w;    w += (size_t)NNODES * 4 * 4;
  float* denom = (float*)w; w += (size_t)NNODES * 4 * 4;
  int* counts = (int*)w;    w += (size_t)NNODES * 4;
  int* cursor = (int*)w;    w += (size_t)NNODES * 4;
  int* row_ptr = (int*)w;   w += (size_t)(NNODES + 1) * 4;
  int* edge_list = (int*)w; w += (size_t)NEDGES * 4;

  hipMemsetAsync(segmax, 0, (size_t)NNODES * 16, stream);  // mapped -inf == 0
  hipMemsetAsync(denom, 0, (size_t)NNODES * 16, stream);
  hipMemsetAsync(counts, 0, (size_t)NNODES * 4, stream);
  hipMemsetAsync(cursor, 0, (size_t)NNODES * 4, stream);

  k_gemm<<<(NNODES + 63) / 64, 256, 0, stream>>>(x, W, hf, hb);
  k_scores<<<(NNODES * HEADS + 255) / 256, 256, 0, stream>>>(hf, attn, s_src, s_dst);
  k_hist<<<(NEDGES + 255) / 256, 256, 0, stream>>>(rowi, counts);
  k_scan<<<1, 1024, 0, stream>>>(counts, row_ptr);
  k_scatter<<<(NEDGES + 255) / 256, 256, 0, stream>>>(rowi, row_ptr, cursor, edge_list);
  k_alpha<<<(NEDGES + 255) / 256, 256, 0, stream>>>(rowi, coli, s_src, s_dst, alpha_out, segmax);
  k_ex<<<(NEDGES + 255) / 256, 256, 0, stream>>>(rowi, alpha_out, segmax, denom);
  k_aggr<<<(NNODES + 3) / 4, 256, 0, stream>>>(coli, row_ptr, edge_list, denom, hb, alpha_out, out_mean);
}

// Round 2
// 577.167 us; speedup vs baseline: 2.0551x; 2.0551x over previous
//
#include <hip/hip_runtime.h>

#define NNODES 50000
#define NEDGES 1600000
#define IN_CH 256
#define HEADS 4
#define OUT_CH 32
#define HC 128  // HEADS*OUT_CH

typedef unsigned int u32;
typedef unsigned short u16;

__device__ __forceinline__ float b2f(u16 s) { return __uint_as_float(((u32)s) << 16); }
__device__ __forceinline__ u16 f2b(float f) {
  u32 u = __float_as_uint(f);
  u32 r = (u + 0x7FFFu + ((u >> 16) & 1u)) >> 16;
  return (u16)r;
}
__device__ __forceinline__ float lrelu(float v) { return v >= 0.f ? v : 0.2f * v; }

// ---- K1: h = x @ W  (50000x256 @ 256x128), store f32 + bf16 copies ----
__global__ __launch_bounds__(256) void k_gemm(const float* __restrict__ x,
                                              const float* __restrict__ W,
                                              float* __restrict__ hf,
                                              u16* __restrict__ hb) {
  __shared__ float xsT[32][64];   // [k][row]
  __shared__ float Ws[32][128];   // [k][col]
  const int tid = threadIdx.x;
  const int row0 = blockIdx.x * 64;
  const int tc = tid & 31;   // col group: cols tc*4..+3
  const int tr = tid >> 5;   // row group: rows tr*8..+7
  float4 acc[8];
#pragma unroll
  for (int i = 0; i < 8; ++i) acc[i] = make_float4(0.f, 0.f, 0.f, 0.f);

  for (int kt = 0; kt < IN_CH; kt += 32) {
#pragma unroll
    for (int li = 0; li < 2; ++li) {
      int f4i = tid + li * 256;          // 0..511
      int r = f4i >> 3;
      int kc = (f4i & 7) << 2;
      int grow = row0 + r;
      float4 v = make_float4(0.f, 0.f, 0.f, 0.f);
      if (grow < NNODES) v = *(const float4*)&x[(size_t)grow * IN_CH + kt + kc];
      xsT[kc + 0][r] = v.x;
      xsT[kc + 1][r] = v.y;
      xsT[kc + 2][r] = v.z;
      xsT[kc + 3][r] = v.w;
    }
#pragma unroll
    for (int li = 0; li < 4; ++li) {
      int f4i = tid + li * 256;          // 0..1023
      int kk = f4i >> 5;
      int c4 = (f4i & 31) << 2;
      *(float4*)&Ws[kk][c4] = *(const float4*)&W[(size_t)(kt + kk) * HC + c4];
    }
    __syncthreads();
#pragma unroll 4
    for (int kk = 0; kk < 32; ++kk) {
      float4 b = *(const float4*)&Ws[kk][tc << 2];
      float4 a0 = *(const float4*)&xsT[kk][tr << 3];
      float4 a1 = *(const float4*)&xsT[kk][(tr << 3) + 4];
      float av[8] = {a0.x, a0.y, a0.z, a0.w, a1.x, a1.y, a1.z, a1.w};
#pragma unroll
      for (int i = 0; i < 8; ++i) {
        acc[i].x += av[i] * b.x;
        acc[i].y += av[i] * b.y;
        acc[i].z += av[i] * b.z;
        acc[i].w += av[i] * b.w;
      }
    }
    __syncthreads();
  }
#pragma unroll
  for (int i = 0; i < 8; ++i) {
    int grow = row0 + (tr << 3) + i;
    if (grow < NNODES) {
      *(float4*)&hf[(size_t)grow * HC + (tc << 2)] = acc[i];
      u16 q[4] = {f2b(acc[i].x), f2b(acc[i].y), f2b(acc[i].z), f2b(acc[i].w)};
      *(ushort4*)&hb[(size_t)grow * HC + (tc << 2)] = *(ushort4*)q;
    }
  }
}

// ---- K2: per-node attention scores (fp32 h for exact logits) ----
__global__ __launch_bounds__(256) void k_scores(const float* __restrict__ hf,
                                                const float* __restrict__ attn,
                                                float* __restrict__ s_src,
                                                float* __restrict__ s_dst) {
  int idx = blockIdx.x * 256 + threadIdx.x;
  if (idx >= NNODES * HEADS) return;
  int n = idx >> 2, hd = idx & 3;
  const float* hrow = hf + (size_t)n * HC + hd * OUT_CH;
  const float* arow = attn + hd * 64;
  float ss = 0.f, sd = 0.f;
#pragma unroll
  for (int c = 0; c < OUT_CH; ++c) {
    float hv = hrow[c];
    ss += hv * arow[c];
    sd += hv * arow[32 + c];
  }
  s_src[idx] = ss;
  s_dst[idx] = sd;
}

// ---- K3: degree histogram ----
__global__ void k_hist(const int* __restrict__ rowi, int* __restrict__ counts) {
  int e = blockIdx.x * 256 + threadIdx.x;
  if (e < NEDGES) atomicAdd(&counts[rowi[e]], 1);
}

// ---- K4: exclusive prefix sum (single block) ----
__global__ __launch_bounds__(1024) void k_scan(const int* __restrict__ counts,
                                               int* __restrict__ row_ptr) {
  __shared__ int sums[1024];
  const int t = threadIdx.x;
  const int CH = (NNODES + 1023) / 1024;  // 49
  int base = t * CH;
  int s = 0;
  for (int i = 0; i < CH; ++i) {
    int idx = base + i;
    if (idx < NNODES) s += counts[idx];
  }
  sums[t] = s;
  __syncthreads();
  for (int off = 1; off < 1024; off <<= 1) {
    int v = (t >= off) ? sums[t - off] : 0;
    __syncthreads();
    sums[t] += v;
    __syncthreads();
  }
  int run = (t == 0) ? 0 : sums[t - 1];
  for (int i = 0; i < CH; ++i) {
    int idx = base + i;
    if (idx < NNODES) {
      row_ptr[idx] = run;
      run += counts[idx];
    }
  }
  if (t == 1023) row_ptr[NNODES] = run;
}

// ---- K5: scatter (edge_id, col) into CSR buckets ----
__global__ void k_scatter(const int* __restrict__ rowi, const int* __restrict__ coli,
                          const int* __restrict__ row_ptr,
                          int* __restrict__ cursor, int2* __restrict__ el2) {
  int e = blockIdx.x * 256 + threadIdx.x;
  if (e < NEDGES) {
    int r = rowi[e];
    int pos = row_ptr[r] + atomicAdd(&cursor[r], 1);
    el2[pos] = make_int2(e, coli[e]);
  }
}

// ---- K6: per-row wave softmax, zero atomics.
// Writes alpha_norm to its final d_out slot (scattered by edge id) AND to
// an_buf indexed by CSR position (coalesced) for the aggregation kernel. ----
__global__ __launch_bounds__(256) void k_softmax(const int2* __restrict__ el2,
                                                 const int* __restrict__ row_ptr,
                                                 const float* __restrict__ s_src,
                                                 const float* __restrict__ s_dst,
                                                 float* __restrict__ alpha_out,
                                                 float* __restrict__ an_buf) {
  const int wid = threadIdx.x >> 6;
  const int lane = threadIdx.x & 63;
  const int r = blockIdx.x * 4 + wid;
  if (r >= NNODES) return;
  const int p0 = row_ptr[r], p1 = row_ptr[r + 1];
  const int deg = p1 - p0;
  if (deg == 0) return;
  const float4 ss = *(const float4*)&s_src[(size_t)r * 4];
  const float NEG = -3.0e38f;

  if (deg <= 64) {  // ~always (Poisson mean 32): alphas stay in registers
    int2 ec = make_int2(0, 0);
    float4 al = make_float4(NEG, NEG, NEG, NEG);
    if (lane < deg) {
      ec = el2[p0 + lane];
      float4 sd = *(const float4*)&s_dst[(size_t)ec.y * 4];
      al.x = lrelu(ss.x + sd.x);
      al.y = lrelu(ss.y + sd.y);
      al.z = lrelu(ss.z + sd.z);
      al.w = lrelu(ss.w + sd.w);
    }
    float4 mx = al;
#pragma unroll
    for (int m = 1; m < 64; m <<= 1) {
      mx.x = fmaxf(mx.x, __shfl_xor(mx.x, m));
      mx.y = fmaxf(mx.y, __shfl_xor(mx.y, m));
      mx.z = fmaxf(mx.z, __shfl_xor(mx.z, m));
      mx.w = fmaxf(mx.w, __shfl_xor(mx.w, m));
    }
    float4 ex = make_float4(0.f, 0.f, 0.f, 0.f);
    if (lane < deg) {
      ex.x = __expf(al.x - mx.x);
      ex.y = __expf(al.y - mx.y);
      ex.z = __expf(al.z - mx.z);
      ex.w = __expf(al.w - mx.w);
    }
    float4 sm = ex;
#pragma unroll
    for (int m = 1; m < 64; m <<= 1) {
      sm.x += __shfl_xor(sm.x, m);
      sm.y += __shfl_xor(sm.y, m);
      sm.z += __shfl_xor(sm.z, m);
      sm.w += __shfl_xor(sm.w, m);
    }
    if (lane < deg) {
      float4 an = make_float4(ex.x / sm.x, ex.y / sm.y, ex.z / sm.z, ex.w / sm.w);
      *(float4*)&alpha_out[(size_t)ec.x * 4] = an;
      *(float4*)&an_buf[(size_t)(p0 + lane) * 4] = an;
    }
  } else {  // rare general path
    float4 mx = make_float4(NEG, NEG, NEG, NEG);
    for (int p = p0 + lane; p < p1; p += 64) {
      int2 ec = el2[p];
      float4 sd = *(const float4*)&s_dst[(size_t)ec.y * 4];
      mx.x = fmaxf(mx.x, lrelu(ss.x + sd.x));
      mx.y = fmaxf(mx.y, lrelu(ss.y + sd.y));
      mx.z = fmaxf(mx.z, lrelu(ss.z + sd.z));
      mx.w = fmaxf(mx.w, lrelu(ss.w + sd.w));
    }
#pragma unroll
    for (int m = 1; m < 64; m <<= 1) {
      mx.x = fmaxf(mx.x, __shfl_xor(mx.x, m));
      mx.y = fmaxf(mx.y, __shfl_xor(mx.y, m));
      mx.z = fmaxf(mx.z, __shfl_xor(mx.z, m));
      mx.w = fmaxf(mx.w, __shfl_xor(mx.w, m));
    }
    float4 sm = make_float4(0.f, 0.f, 0.f, 0.f);
    for (int p = p0 + lane; p < p1; p += 64) {
      int2 ec = el2[p];
      float4 sd = *(const float4*)&s_dst[(size_t)ec.y * 4];
      float4 ex;
      ex.x = __expf(lrelu(ss.x + sd.x) - mx.x);
      ex.y = __expf(lrelu(ss.y + sd.y) - mx.y);
      ex.z = __expf(lrelu(ss.z + sd.z) - mx.z);
      ex.w = __expf(lrelu(ss.w + sd.w) - mx.w);
      *(float4*)&an_buf[(size_t)p * 4] = ex;
      sm.x += ex.x; sm.y += ex.y; sm.z += ex.z; sm.w += ex.w;
    }
#pragma unroll
    for (int m = 1; m < 64; m <<= 1) {
      sm.x += __shfl_xor(sm.x, m);
      sm.y += __shfl_xor(sm.y, m);
      sm.z += __shfl_xor(sm.z, m);
      sm.w += __shfl_xor(sm.w, m);
    }
    for (int p = p0 + lane; p < p1; p += 64) {
      int2 ec = el2[p];
      float4 ex = *(const float4*)&an_buf[(size_t)p * 4];
      float4 an = make_float4(ex.x / sm.x, ex.y / sm.y, ex.z / sm.z, ex.w / sm.w);
      *(float4*)&an_buf[(size_t)p * 4] = an;
      *(float4*)&alpha_out[(size_t)ec.x * 4] = an;
    }
  }
}

// ---- K7: per-row wave aggregation: out[r] = mean_h sum_e an[e,h] * h_b[col,h,:] ----
__global__ __launch_bounds__(256) void k_aggr(const int2* __restrict__ el2,
                                              const int* __restrict__ row_ptr,
                                              const float* __restrict__ an_buf,
                                              const u16* __restrict__ hb,
                                              float* __restrict__ out_mean) {
  const int wid = threadIdx.x >> 6;
  const int lane = threadIdx.x & 63;
  const int r = blockIdx.x * 4 + wid;
  if (r >= NNODES) return;
  const int p0 = row_ptr[r], p1 = row_ptr[r + 1];
  const int hd = lane >> 4;
  float acc0 = 0.f, acc1 = 0.f;

  int c = 0;
  if (p0 < p1) c = el2[p0].y;
  for (int p = p0; p < p1; ++p) {
    int cn = 0;
    if (p + 1 < p1) cn = el2[p + 1].y;
    float4 an = *(const float4*)&an_buf[(size_t)p * 4];
    float w = (hd == 0) ? an.x : (hd == 1) ? an.y : (hd == 2) ? an.z : an.w;
    u32 hv = *(const u32*)&hb[(size_t)c * HC + (lane << 1)];
    acc0 += w * b2f((u16)(hv & 0xFFFFu));
    acc1 += w * b2f((u16)(hv >> 16));
    c = cn;
  }
  acc0 += __shfl_xor(acc0, 16);
  acc0 += __shfl_xor(acc0, 32);
  acc1 += __shfl_xor(acc1, 16);
  acc1 += __shfl_xor(acc1, 32);
  if (lane < 16) {
    float2 o = make_float2(acc0 * 0.25f, acc1 * 0.25f);
    *(float2*)&out_mean[(size_t)r * 32 + (lane << 1)] = o;
  }
}

extern "C" void kernel_launch(void* const* d_in, const int* in_sizes, int n_in,
                              void* d_out, int out_size, void* d_ws, size_t ws_size,
                              hipStream_t stream) {
  const float* x = (const float*)d_in[0];
  const int* ei = (const int*)d_in[1];
  const float* W = (const float*)d_in[2];
  const float* attn = (const float*)d_in[3];
  const int* rowi = ei;
  const int* coli = ei + NEDGES;

  float* out_mean = (float*)d_out;
  float* alpha_out = (float*)d_out + (size_t)NNODES * 32;

  char* w = (char*)d_ws;
  u16* hb = (u16*)w;        w += (size_t)NNODES * HC * 2;       // 12.8 MB
  float* hf = (float*)w;    w += (size_t)NNODES * HC * 4;       // 25.6 MB (reused as an_buf)
  float* s_src = (float*)w; w += (size_t)NNODES * 4 * 4;
  float* s_dst = (float*)w; w += (size_t)NNODES * 4 * 4;
  int* counts = (int*)w;    w += (size_t)NNODES * 4;
  int* cursor = (int*)w;    w += (size_t)NNODES * 4;
  int* row_ptr = (int*)w;   w += (size_t)(NNODES + 1) * 4;
  int2* el2 = (int2*)w;     w += (size_t)NEDGES * 8;            // 12.8 MB
  // an_buf aliases hf: hf's last reader (k_scores) finishes before k_softmax writes.
  float* an_buf = hf;

  hipMemsetAsync(counts, 0, (size_t)NNODES * 4, stream);
  hipMemsetAsync(cursor, 0, (size_t)NNODES * 4, stream);

  k_gemm<<<(NNODES + 63) / 64, 256, 0, stream>>>(x, W, hf, hb);
  k_scores<<<(NNODES * HEADS + 255) / 256, 256, 0, stream>>>(hf, attn, s_src, s_dst);
  k_hist<<<(NEDGES + 255) / 256, 256, 0, stream>>>(rowi, counts);
  k_scan<<<1, 1024, 0, stream>>>(counts, row_ptr);
  k_scatter<<<(NEDGES + 255) / 256, 256, 0, stream>>>(rowi, coli, row_ptr, cursor, el2);
  k_softmax<<<(NNODES + 3) / 4, 256, 0, stream>>>(el2, row_ptr, s_src, s_dst, alpha_out, an_buf);
  k_aggr<<<(NNODES + 3) / 4, 256, 0, stream>>>(el2, row_ptr, an_buf, hb, out_mean);
}

// Round 3
// 282.333 us; speedup vs baseline: 4.2011x; 2.0443x over previous
//
#include <hip/hip_runtime.h>

#define NNODES 50000
#define NEDGES 1600000
#define IN_CH 256
#define HEADS 4
#define OUT_CH 32
#define HC 128  // HEADS*OUT_CH
#define NSB ((NNODES + 255) / 256)  // scan blocks = 196

typedef unsigned int u32;
typedef unsigned short u16;

__device__ __forceinline__ float b2f(u16 s) { return __uint_as_float(((u32)s) << 16); }
__device__ __forceinline__ u16 f2b(float f) {
  u32 u = __float_as_uint(f);
  u32 r = (u + 0x7FFFu + ((u >> 16) & 1u)) >> 16;
  return (u16)r;
}
__device__ __forceinline__ float lrelu(float v) { return v >= 0.f ? v : 0.2f * v; }

// ---- K1: h = x @ W  (50000x256 @ 256x128), store f32 + bf16 copies ----
__global__ __launch_bounds__(256) void k_gemm(const float* __restrict__ x,
                                              const float* __restrict__ W,
                                              float* __restrict__ hf,
                                              u16* __restrict__ hb) {
  __shared__ float xsT[32][64];   // [k][row]
  __shared__ float Ws[32][128];   // [k][col]
  const int tid = threadIdx.x;
  const int row0 = blockIdx.x * 64;
  const int tc = tid & 31;
  const int tr = tid >> 5;
  float4 acc[8];
#pragma unroll
  for (int i = 0; i < 8; ++i) acc[i] = make_float4(0.f, 0.f, 0.f, 0.f);

  for (int kt = 0; kt < IN_CH; kt += 32) {
#pragma unroll
    for (int li = 0; li < 2; ++li) {
      int f4i = tid + li * 256;
      int r = f4i >> 3;
      int kc = (f4i & 7) << 2;
      int grow = row0 + r;
      float4 v = make_float4(0.f, 0.f, 0.f, 0.f);
      if (grow < NNODES) v = *(const float4*)&x[(size_t)grow * IN_CH + kt + kc];
      xsT[kc + 0][r] = v.x;
      xsT[kc + 1][r] = v.y;
      xsT[kc + 2][r] = v.z;
      xsT[kc + 3][r] = v.w;
    }
#pragma unroll
    for (int li = 0; li < 4; ++li) {
      int f4i = tid + li * 256;
      int kk = f4i >> 5;
      int c4 = (f4i & 31) << 2;
      *(float4*)&Ws[kk][c4] = *(const float4*)&W[(size_t)(kt + kk) * HC + c4];
    }
    __syncthreads();
#pragma unroll 4
    for (int kk = 0; kk < 32; ++kk) {
      float4 b = *(const float4*)&Ws[kk][tc << 2];
      float4 a0 = *(const float4*)&xsT[kk][tr << 3];
      float4 a1 = *(const float4*)&xsT[kk][(tr << 3) + 4];
      float av[8] = {a0.x, a0.y, a0.z, a0.w, a1.x, a1.y, a1.z, a1.w};
#pragma unroll
      for (int i = 0; i < 8; ++i) {
        acc[i].x += av[i] * b.x;
        acc[i].y += av[i] * b.y;
        acc[i].z += av[i] * b.z;
        acc[i].w += av[i] * b.w;
      }
    }
    __syncthreads();
  }
#pragma unroll
  for (int i = 0; i < 8; ++i) {
    int grow = row0 + (tr << 3) + i;
    if (grow < NNODES) {
      *(float4*)&hf[(size_t)grow * HC + (tc << 2)] = acc[i];
      u16 q[4] = {f2b(acc[i].x), f2b(acc[i].y), f2b(acc[i].z), f2b(acc[i].w)};
      *(ushort4*)&hb[(size_t)grow * HC + (tc << 2)] = *(ushort4*)q;
    }
  }
}

// ---- K2: per-node attention scores (fp32 h for exact logits) ----
__global__ __launch_bounds__(256) void k_scores(const float* __restrict__ hf,
                                                const float* __restrict__ attn,
                                                float* __restrict__ s_src,
                                                float* __restrict__ s_dst) {
  int idx = blockIdx.x * 256 + threadIdx.x;
  if (idx >= NNODES * HEADS) return;
  int n = idx >> 2, hd = idx & 3;
  const float* hrow = hf + (size_t)n * HC + hd * OUT_CH;
  const float* arow = attn + hd * 64;
  float ss = 0.f, sd = 0.f;
#pragma unroll
  for (int c = 0; c < OUT_CH; ++c) {
    float hv = hrow[c];
    ss += hv * arow[c];
    sd += hv * arow[32 + c];
  }
  s_src[idx] = ss;
  s_dst[idx] = sd;
}

// ---- K3: degree histogram + per-edge slot (makes scatter atomic-free) ----
__global__ void k_hist(const int* __restrict__ rowi, int* __restrict__ counts,
                       int* __restrict__ slot) {
  int e = blockIdx.x * 256 + threadIdx.x;
  if (e < NEDGES) slot[e] = atomicAdd(&counts[rowi[e]], 1);
}

// ---- K4a/b/c: full-GPU 3-phase exclusive scan of counts -> row_ptr ----
__global__ __launch_bounds__(256) void k_scan1(const int* __restrict__ counts,
                                               int* __restrict__ bsum) {
  int i = blockIdx.x * 256 + threadIdx.x;
  int v = (i < NNODES) ? counts[i] : 0;
#pragma unroll
  for (int m = 1; m < 64; m <<= 1) v += __shfl_xor(v, m);
  __shared__ int ws[4];
  if ((threadIdx.x & 63) == 0) ws[threadIdx.x >> 6] = v;
  __syncthreads();
  if (threadIdx.x == 0) bsum[blockIdx.x] = ws[0] + ws[1] + ws[2] + ws[3];
}

__global__ __launch_bounds__(256) void k_scan2(const int* __restrict__ bsum,
                                               int* __restrict__ boff) {
  __shared__ int s[256];
  int t = threadIdx.x;
  int v = (t < NSB) ? bsum[t] : 0;
  s[t] = v;
  __syncthreads();
  for (int off = 1; off < 256; off <<= 1) {
    int u = (t >= off) ? s[t - off] : 0;
    __syncthreads();
    s[t] += u;
    __syncthreads();
  }
  boff[t] = s[t] - v;  // exclusive
}

__global__ __launch_bounds__(256) void k_scan3(const int* __restrict__ counts,
                                               const int* __restrict__ boff,
                                               int* __restrict__ row_ptr) {
  __shared__ int s[256];
  int t = threadIdx.x;
  int i = blockIdx.x * 256 + t;
  int v = (i < NNODES) ? counts[i] : 0;
  s[t] = v;
  __syncthreads();
  for (int off = 1; off < 256; off <<= 1) {
    int u = (t >= off) ? s[t - off] : 0;
    __syncthreads();
    s[t] += u;
    __syncthreads();
  }
  if (i < NNODES) row_ptr[i] = boff[blockIdx.x] + s[t] - v;
  if (i == 0) row_ptr[NNODES] = NEDGES;
}

// ---- K5: scatter edge id + col into CSR (no atomics) ----
__global__ void k_scatter(const int* __restrict__ rowi, const int* __restrict__ coli,
                          const int* __restrict__ row_ptr, const int* __restrict__ slot,
                          int* __restrict__ eid_csr, int* __restrict__ col_csr) {
  int e = blockIdx.x * 256 + threadIdx.x;
  if (e < NEDGES) {
    int pos = row_ptr[rowi[e]] + slot[e];
    eid_csr[pos] = e;
    col_csr[pos] = coli[e];
  }
}

// ---- K6: per-row wave softmax, zero atomics ----
__global__ __launch_bounds__(256) void k_softmax(const int* __restrict__ eid_csr,
                                                 const int* __restrict__ col_csr,
                                                 const int* __restrict__ row_ptr,
                                                 const float* __restrict__ s_src,
                                                 const float* __restrict__ s_dst,
                                                 float* __restrict__ alpha_out,
                                                 float* __restrict__ an_buf) {
  const int wid = threadIdx.x >> 6;
  const int lane = threadIdx.x & 63;
  const int r = blockIdx.x * 4 + wid;
  if (r >= NNODES) return;
  const int p0 = row_ptr[r], p1 = row_ptr[r + 1];
  const int deg = p1 - p0;
  if (deg == 0) return;
  const float4 ss = *(const float4*)&s_src[(size_t)r * 4];
  const float NEG = -3.0e38f;

  if (deg <= 64) {
    int e = 0, c = 0;
    float4 al = make_float4(NEG, NEG, NEG, NEG);
    if (lane < deg) {
      e = eid_csr[p0 + lane];
      c = col_csr[p0 + lane];
      float4 sd = *(const float4*)&s_dst[(size_t)c * 4];
      al.x = lrelu(ss.x + sd.x);
      al.y = lrelu(ss.y + sd.y);
      al.z = lrelu(ss.z + sd.z);
      al.w = lrelu(ss.w + sd.w);
    }
    float4 mx = al;
#pragma unroll
    for (int m = 1; m < 64; m <<= 1) {
      mx.x = fmaxf(mx.x, __shfl_xor(mx.x, m));
      mx.y = fmaxf(mx.y, __shfl_xor(mx.y, m));
      mx.z = fmaxf(mx.z, __shfl_xor(mx.z, m));
      mx.w = fmaxf(mx.w, __shfl_xor(mx.w, m));
    }
    float4 ex = make_float4(0.f, 0.f, 0.f, 0.f);
    if (lane < deg) {
      ex.x = __expf(al.x - mx.x);
      ex.y = __expf(al.y - mx.y);
      ex.z = __expf(al.z - mx.z);
      ex.w = __expf(al.w - mx.w);
    }
    float4 sm = ex;
#pragma unroll
    for (int m = 1; m < 64; m <<= 1) {
      sm.x += __shfl_xor(sm.x, m);
      sm.y += __shfl_xor(sm.y, m);
      sm.z += __shfl_xor(sm.z, m);
      sm.w += __shfl_xor(sm.w, m);
    }
    if (lane < deg) {
      float4 an = make_float4(ex.x / sm.x, ex.y / sm.y, ex.z / sm.z, ex.w / sm.w);
      *(float4*)&alpha_out[(size_t)e * 4] = an;
      *(float4*)&an_buf[(size_t)(p0 + lane) * 4] = an;
    }
  } else {
    float4 mx = make_float4(NEG, NEG, NEG, NEG);
    for (int p = p0 + lane; p < p1; p += 64) {
      int c = col_csr[p];
      float4 sd = *(const float4*)&s_dst[(size_t)c * 4];
      mx.x = fmaxf(mx.x, lrelu(ss.x + sd.x));
      mx.y = fmaxf(mx.y, lrelu(ss.y + sd.y));
      mx.z = fmaxf(mx.z, lrelu(ss.z + sd.z));
      mx.w = fmaxf(mx.w, lrelu(ss.w + sd.w));
    }
#pragma unroll
    for (int m = 1; m < 64; m <<= 1) {
      mx.x = fmaxf(mx.x, __shfl_xor(mx.x, m));
      mx.y = fmaxf(mx.y, __shfl_xor(mx.y, m));
      mx.z = fmaxf(mx.z, __shfl_xor(mx.z, m));
      mx.w = fmaxf(mx.w, __shfl_xor(mx.w, m));
    }
    float4 sm = make_float4(0.f, 0.f, 0.f, 0.f);
    for (int p = p0 + lane; p < p1; p += 64) {
      int c = col_csr[p];
      float4 sd = *(const float4*)&s_dst[(size_t)c * 4];
      float4 ex;
      ex.x = __expf(lrelu(ss.x + sd.x) - mx.x);
      ex.y = __expf(lrelu(ss.y + sd.y) - mx.y);
      ex.z = __expf(lrelu(ss.z + sd.z) - mx.z);
      ex.w = __expf(lrelu(ss.w + sd.w) - mx.w);
      *(float4*)&an_buf[(size_t)p * 4] = ex;
      sm.x += ex.x; sm.y += ex.y; sm.z += ex.z; sm.w += ex.w;
    }
#pragma unroll
    for (int m = 1; m < 64; m <<= 1) {
      sm.x += __shfl_xor(sm.x, m);
      sm.y += __shfl_xor(sm.y, m);
      sm.z += __shfl_xor(sm.z, m);
      sm.w += __shfl_xor(sm.w, m);
    }
    for (int p = p0 + lane; p < p1; p += 64) {
      int e = eid_csr[p];
      float4 ex = *(const float4*)&an_buf[(size_t)p * 4];
      float4 an = make_float4(ex.x / sm.x, ex.y / sm.y, ex.z / sm.z, ex.w / sm.w);
      *(float4*)&an_buf[(size_t)p * 4] = an;
      *(float4*)&alpha_out[(size_t)e * 4] = an;
    }
  }
}

// ---- K7: per-row wave aggregation, 8-deep gather pipeline ----
__global__ __launch_bounds__(256) void k_aggr(const int* __restrict__ col_csr,
                                              const int* __restrict__ row_ptr,
                                              const float* __restrict__ an_buf,
                                              const u16* __restrict__ hb,
                                              float* __restrict__ out_mean) {
  const int wid = threadIdx.x >> 6;
  const int lane = threadIdx.x & 63;
  const int r = blockIdx.x * 4 + wid;
  if (r >= NNODES) return;
  const int p0 = row_ptr[r], p1 = row_ptr[r + 1];
  const int hd = lane >> 4;
  const int ch = lane << 1;
  float acc0 = 0.f, acc1 = 0.f;

  int p = p0;
  for (; p + 8 <= p1; p += 8) {
    int cs[8];
    float ws[8];
    u32 hv[8];
#pragma unroll
    for (int i = 0; i < 8; ++i) cs[i] = col_csr[p + i];
#pragma unroll
    for (int i = 0; i < 8; ++i) ws[i] = an_buf[(size_t)(p + i) * 4 + hd];
#pragma unroll
    for (int i = 0; i < 8; ++i) hv[i] = *(const u32*)&hb[(size_t)cs[i] * HC + ch];
#pragma unroll
    for (int i = 0; i < 8; ++i) {
      acc0 += ws[i] * b2f((u16)(hv[i] & 0xFFFFu));
      acc1 += ws[i] * b2f((u16)(hv[i] >> 16));
    }
  }
  for (; p < p1; ++p) {
    int c = col_csr[p];
    float w = an_buf[(size_t)p * 4 + hd];
    u32 hv = *(const u32*)&hb[(size_t)c * HC + ch];
    acc0 += w * b2f((u16)(hv & 0xFFFFu));
    acc1 += w * b2f((u16)(hv >> 16));
  }
  acc0 += __shfl_xor(acc0, 16);
  acc0 += __shfl_xor(acc0, 32);
  acc1 += __shfl_xor(acc1, 16);
  acc1 += __shfl_xor(acc1, 32);
  if (lane < 16) {
    float2 o = make_float2(acc0 * 0.25f, acc1 * 0.25f);
    *(float2*)&out_mean[(size_t)r * 32 + (lane << 1)] = o;
  }
}

extern "C" void kernel_launch(void* const* d_in, const int* in_sizes, int n_in,
                              void* d_out, int out_size, void* d_ws, size_t ws_size,
                              hipStream_t stream) {
  const float* x = (const float*)d_in[0];
  const int* ei = (const int*)d_in[1];
  const float* W = (const float*)d_in[2];
  const float* attn = (const float*)d_in[3];
  const int* rowi = ei;
  const int* coli = ei + NEDGES;

  float* out_mean = (float*)d_out;
  float* alpha_out = (float*)d_out + (size_t)NNODES * 32;

  char* w = (char*)d_ws;
  u16* hb = (u16*)w;         w += (size_t)NNODES * HC * 2;       // 12.8 MB
  float* hf = (float*)w;     w += (size_t)NNODES * HC * 4;       // 25.6 MB (reused as an_buf)
  float* s_src = (float*)w;  w += (size_t)NNODES * 4 * 4;
  float* s_dst = (float*)w;  w += (size_t)NNODES * 4 * 4;
  int* counts = (int*)w;     w += (size_t)NNODES * 4;
  int* bsum = (int*)w;       w += (size_t)256 * 4;
  int* boff = (int*)w;       w += (size_t)256 * 4;
  int* row_ptr = (int*)w;    w += (size_t)(NNODES + 1) * 4;
  int* slot = (int*)w;       w += (size_t)NEDGES * 4;            // 6.4 MB
  int* eid_csr = (int*)w;    w += (size_t)NEDGES * 4;            // 6.4 MB
  int* col_csr = (int*)w;    w += (size_t)NEDGES * 4;            // 6.4 MB
  float* an_buf = hf;  // hf's last reader (k_scores) precedes k_softmax's writes

  hipMemsetAsync(counts, 0, (size_t)NNODES * 4, stream);

  k_gemm<<<(NNODES + 63) / 64, 256, 0, stream>>>(x, W, hf, hb);
  k_scores<<<(NNODES * HEADS + 255) / 256, 256, 0, stream>>>(hf, attn, s_src, s_dst);
  k_hist<<<(NEDGES + 255) / 256, 256, 0, stream>>>(rowi, counts, slot);
  k_scan1<<<NSB, 256, 0, stream>>>(counts, bsum);
  k_scan2<<<1, 256, 0, stream>>>(bsum, boff);
  k_scan3<<<NSB, 256, 0, stream>>>(counts, boff, row_ptr);
  k_scatter<<<(NEDGES + 255) / 256, 256, 0, stream>>>(rowi, coli, row_ptr, slot, eid_csr, col_csr);
  k_softmax<<<(NNODES + 3) / 4, 256, 0, stream>>>(eid_csr, col_csr, row_ptr, s_src, s_dst, alpha_out, an_buf);
  k_aggr<<<(NNODES + 3) / 4, 256, 0, stream>>>(col_csr, row_ptr, an_buf, hb, out_mean);
}

// Round 4
// 249.298 us; speedup vs baseline: 4.7579x; 1.1325x over previous
//
#include <hip/hip_runtime.h>

#define NNODES 50000
#define NEDGES 1600000
#define IN_CH 256
#define HEADS 4
#define OUT_CH 32
#define HC 128                       // HEADS*OUT_CH
#define NSB ((NNODES + 255) / 256)   // 196 scan blocks
#define NCHUNK 128
#define CE 12500                     // edges per chunk; 128*12500 == NEDGES exactly
#define WORDS 25000                  // u32 words per chunk hist (2 u16 bins/word)

typedef unsigned int u32;
typedef unsigned short u16;

__device__ __forceinline__ float b2f(u16 s) { return __uint_as_float(((u32)s) << 16); }
__device__ __forceinline__ u16 f2b(float f) {
  u32 u = __float_as_uint(f);
  u32 r = (u + 0x7FFFu + ((u >> 16) & 1u)) >> 16;
  return (u16)r;
}
__device__ __forceinline__ float lrelu(float v) { return v >= 0.f ? v : 0.2f * v; }

// ---- K1: h = x @ W, fused: bf16 h store + per-node scores (fp32 logits) ----
__global__ __launch_bounds__(256) void k_gemm(const float* __restrict__ x,
                                              const float* __restrict__ W,
                                              const float* __restrict__ attn,
                                              u16* __restrict__ hb,
                                              float* __restrict__ s_src,
                                              float* __restrict__ s_dst) {
  __shared__ float xsT[32][64];   // [k][row]
  __shared__ float Ws[32][128];   // [k][col]
  __shared__ float sA[256];       // attn flat [h][64]
  const int tid = threadIdx.x;
  const int row0 = blockIdx.x * 64;
  const int tc = tid & 31;
  const int tr = tid >> 5;
  sA[tid] = attn[tid];
  float4 acc[8];
#pragma unroll
  for (int i = 0; i < 8; ++i) acc[i] = make_float4(0.f, 0.f, 0.f, 0.f);

  for (int kt = 0; kt < IN_CH; kt += 32) {
#pragma unroll
    for (int li = 0; li < 2; ++li) {
      int f4i = tid + li * 256;
      int r = f4i >> 3;
      int kc = (f4i & 7) << 2;
      int grow = row0 + r;
      float4 v = make_float4(0.f, 0.f, 0.f, 0.f);
      if (grow < NNODES) v = *(const float4*)&x[(size_t)grow * IN_CH + kt + kc];
      xsT[kc + 0][r] = v.x;
      xsT[kc + 1][r] = v.y;
      xsT[kc + 2][r] = v.z;
      xsT[kc + 3][r] = v.w;
    }
#pragma unroll
    for (int li = 0; li < 4; ++li) {
      int f4i = tid + li * 256;
      int kk = f4i >> 5;
      int c4 = (f4i & 31) << 2;
      *(float4*)&Ws[kk][c4] = *(const float4*)&W[(size_t)(kt + kk) * HC + c4];
    }
    __syncthreads();
#pragma unroll 4
    for (int kk = 0; kk < 32; ++kk) {
      float4 b = *(const float4*)&Ws[kk][tc << 2];
      float4 a0 = *(const float4*)&xsT[kk][tr << 3];
      float4 a1 = *(const float4*)&xsT[kk][(tr << 3) + 4];
      float av[8] = {a0.x, a0.y, a0.z, a0.w, a1.x, a1.y, a1.z, a1.w};
#pragma unroll
      for (int i = 0; i < 8; ++i) {
        acc[i].x += av[i] * b.x;
        acc[i].y += av[i] * b.y;
        acc[i].z += av[i] * b.z;
        acc[i].w += av[i] * b.w;
      }
    }
    __syncthreads();
  }
  // epilogue: bf16 h + fused score partials (8-lane-group reduce per head)
  const int head = tc >> 3;
  const int cb = (tc & 7) << 2;
  const float4 as4 = *(const float4*)&sA[head * 64 + cb];
  const float4 ad4 = *(const float4*)&sA[head * 64 + 32 + cb];
#pragma unroll
  for (int i = 0; i < 8; ++i) {
    int grow = row0 + (tr << 3) + i;
    float4 v = acc[i];
    float ps = v.x * as4.x + v.y * as4.y + v.z * as4.z + v.w * as4.w;
    float pd = v.x * ad4.x + v.y * ad4.y + v.z * ad4.z + v.w * ad4.w;
    ps += __shfl_xor(ps, 1); ps += __shfl_xor(ps, 2); ps += __shfl_xor(ps, 4);
    pd += __shfl_xor(pd, 1); pd += __shfl_xor(pd, 2); pd += __shfl_xor(pd, 4);
    if (grow < NNODES) {
      u16 q[4] = {f2b(v.x), f2b(v.y), f2b(v.z), f2b(v.w)};
      *(ushort4*)&hb[(size_t)grow * HC + (tc << 2)] = *(ushort4*)q;
      if ((tc & 7) == 0) {
        s_src[(size_t)grow * 4 + head] = ps;
        s_dst[(size_t)grow * 4 + head] = pd;
      }
    }
  }
}

// ---- K2: chunked LDS histogram (u16-packed), per-edge local slot, no global atomics ----
__global__ __launch_bounds__(256) void k_chist(const int* __restrict__ rowi,
                                               u32* __restrict__ chunk_hist,
                                               u16* __restrict__ lslot) {
  __shared__ u32 lh[WORDS];  // 100 KB
  const int c = blockIdx.x;
  const int tid = threadIdx.x;
  for (int i = tid; i < WORDS; i += 256) lh[i] = 0;
  __syncthreads();
  const int base = c * CE;
  for (int i = tid; i < CE; i += 256) {
    int e = base + i;
    int r = rowi[e];
    u32 sh = (u32)(r & 1) << 4;
    u32 old = atomicAdd(&lh[r >> 1], 1u << sh);
    lslot[e] = (u16)((old >> sh) & 0xFFFFu);
  }
  __syncthreads();
  u32* dst = chunk_hist + (size_t)c * WORDS;
  for (int i = tid; i < WORDS; i += 256) dst[i] = lh[i];
}

// ---- K3: in-place column scan of chunk_hist over chunks; emits per-row totals ----
__global__ __launch_bounds__(256) void k_cscan(u32* __restrict__ chunk_hist,
                                               int* __restrict__ counts) {
  __shared__ u32 tile[NCHUNK][64];  // 32 KB
  const int w0 = blockIdx.x * 64;
  const int tid = threadIdx.x;
  for (int i = tid; i < NCHUNK * 64; i += 256) {
    int c = i >> 6, wl = i & 63;
    int w = w0 + wl;
    tile[c][wl] = (w < WORDS) ? chunk_hist[(size_t)c * WORDS + w] : 0u;
  }
  __syncthreads();
  if (tid < 64) {
    u32 slo = 0, shi = 0;
    for (int c = 0; c < NCHUNK; ++c) {
      u32 v = tile[c][tid];
      tile[c][tid] = slo | (shi << 16);
      slo += v & 0xFFFFu;
      shi += v >> 16;
    }
    int w = w0 + tid;
    if (w < WORDS) {
      int r = w << 1;
      if (r < NNODES) counts[r] = (int)slo;
      if (r + 1 < NNODES) counts[r + 1] = (int)shi;
    }
  }
  __syncthreads();
  for (int i = tid; i < NCHUNK * 64; i += 256) {
    int c = i >> 6, wl = i & 63;
    int w = w0 + wl;
    if (w < WORDS) chunk_hist[(size_t)c * WORDS + w] = tile[c][wl];
  }
}

// ---- K4a/b/c: full-GPU 3-phase exclusive scan of counts -> row_ptr ----
__global__ __launch_bounds__(256) void k_scan1(const int* __restrict__ counts,
                                               int* __restrict__ bsum) {
  int i = blockIdx.x * 256 + threadIdx.x;
  int v = (i < NNODES) ? counts[i] : 0;
#pragma unroll
  for (int m = 1; m < 64; m <<= 1) v += __shfl_xor(v, m);
  __shared__ int ws[4];
  if ((threadIdx.x & 63) == 0) ws[threadIdx.x >> 6] = v;
  __syncthreads();
  if (threadIdx.x == 0) bsum[blockIdx.x] = ws[0] + ws[1] + ws[2] + ws[3];
}

__global__ __launch_bounds__(256) void k_scan2(const int* __restrict__ bsum,
                                               int* __restrict__ boff) {
  __shared__ int s[256];
  int t = threadIdx.x;
  int v = (t < NSB) ? bsum[t] : 0;
  s[t] = v;
  __syncthreads();
  for (int off = 1; off < 256; off <<= 1) {
    int u = (t >= off) ? s[t - off] : 0;
    __syncthreads();
    s[t] += u;
    __syncthreads();
  }
  boff[t] = s[t] - v;
}

__global__ __launch_bounds__(256) void k_scan3(const int* __restrict__ counts,
                                               const int* __restrict__ boff,
                                               int* __restrict__ row_ptr) {
  __shared__ int s[256];
  int t = threadIdx.x;
  int i = blockIdx.x * 256 + t;
  int v = (i < NNODES) ? counts[i] : 0;
  s[t] = v;
  __syncthreads();
  for (int off = 1; off < 256; off <<= 1) {
    int u = (t >= off) ? s[t - off] : 0;
    __syncthreads();
    s[t] += u;
    __syncthreads();
  }
  if (i < NNODES) row_ptr[i] = boff[blockIdx.x] + s[t] - v;
  if (i == 0) row_ptr[NNODES] = NEDGES;
}

// ---- K5: atomic-free scatter of col into CSR ----
__global__ void k_scatter(const int* __restrict__ rowi, const int* __restrict__ coli,
                          const int* __restrict__ row_ptr,
                          const u32* __restrict__ chunk_hist,
                          const u16* __restrict__ lslot,
                          int* __restrict__ col_csr) {
  int e = blockIdx.x * 256 + threadIdx.x;
  if (e >= NEDGES) return;
  int r = rowi[e];
  int c = e / CE;
  u32 word = chunk_hist[(size_t)c * WORDS + (r >> 1)];
  int off = (int)((word >> ((u32)(r & 1) << 4)) & 0xFFFFu);
  int pos = row_ptr[r] + off + (int)lslot[e];
  col_csr[pos] = coli[e];
}

// ---- K6: per-row wave softmax: writes mx, rden (per row) + bf16 an in CSR order ----
__global__ __launch_bounds__(256) void k_softmax(const int* __restrict__ col_csr,
                                                 const int* __restrict__ row_ptr,
                                                 const float* __restrict__ s_src,
                                                 const float* __restrict__ s_dst,
                                                 float* __restrict__ mx_out,
                                                 float* __restrict__ rden_out,
                                                 u16* __restrict__ an16) {
  const int wid = threadIdx.x >> 6;
  const int lane = threadIdx.x & 63;
  const int r = blockIdx.x * 4 + wid;
  if (r >= NNODES) return;
  const int p0 = row_ptr[r], p1 = row_ptr[r + 1];
  const int deg = p1 - p0;
  if (deg == 0) return;
  const float4 ss = *(const float4*)&s_src[(size_t)r * 4];
  const float NEG = -3.0e38f;

  if (deg <= 64) {
    float4 al = make_float4(NEG, NEG, NEG, NEG);
    if (lane < deg) {
      int c = col_csr[p0 + lane];
      float4 sd = *(const float4*)&s_dst[(size_t)c * 4];
      al.x = lrelu(ss.x + sd.x);
      al.y = lrelu(ss.y + sd.y);
      al.z = lrelu(ss.z + sd.z);
      al.w = lrelu(ss.w + sd.w);
    }
    float4 mx = al;
#pragma unroll
    for (int m = 1; m < 64; m <<= 1) {
      mx.x = fmaxf(mx.x, __shfl_xor(mx.x, m));
      mx.y = fmaxf(mx.y, __shfl_xor(mx.y, m));
      mx.z = fmaxf(mx.z, __shfl_xor(mx.z, m));
      mx.w = fmaxf(mx.w, __shfl_xor(mx.w, m));
    }
    float4 ex = make_float4(0.f, 0.f, 0.f, 0.f);
    if (lane < deg) {
      ex.x = __expf(al.x - mx.x);
      ex.y = __expf(al.y - mx.y);
      ex.z = __expf(al.z - mx.z);
      ex.w = __expf(al.w - mx.w);
    }
    float4 sm = ex;
#pragma unroll
    for (int m = 1; m < 64; m <<= 1) {
      sm.x += __shfl_xor(sm.x, m);
      sm.y += __shfl_xor(sm.y, m);
      sm.z += __shfl_xor(sm.z, m);
      sm.w += __shfl_xor(sm.w, m);
    }
    float4 rd = make_float4(1.f / sm.x, 1.f / sm.y, 1.f / sm.z, 1.f / sm.w);
    if (lane == 0) {
      *(float4*)&mx_out[(size_t)r * 4] = mx;
      *(float4*)&rden_out[(size_t)r * 4] = rd;
    }
    if (lane < deg) {
      u16 q[4] = {f2b(ex.x * rd.x), f2b(ex.y * rd.y), f2b(ex.z * rd.z), f2b(ex.w * rd.w)};
      *(ushort4*)&an16[(size_t)(p0 + lane) * 4] = *(ushort4*)q;
    }
  } else {
    float4 mx = make_float4(NEG, NEG, NEG, NEG);
    for (int p = p0 + lane; p < p1; p += 64) {
      int c = col_csr[p];
      float4 sd = *(const float4*)&s_dst[(size_t)c * 4];
      mx.x = fmaxf(mx.x, lrelu(ss.x + sd.x));
      mx.y = fmaxf(mx.y, lrelu(ss.y + sd.y));
      mx.z = fmaxf(mx.z, lrelu(ss.z + sd.z));
      mx.w = fmaxf(mx.w, lrelu(ss.w + sd.w));
    }
#pragma unroll
    for (int m = 1; m < 64; m <<= 1) {
      mx.x = fmaxf(mx.x, __shfl_xor(mx.x, m));
      mx.y = fmaxf(mx.y, __shfl_xor(mx.y, m));
      mx.z = fmaxf(mx.z, __shfl_xor(mx.z, m));
      mx.w = fmaxf(mx.w, __shfl_xor(mx.w, m));
    }
    float4 sm = make_float4(0.f, 0.f, 0.f, 0.f);
    for (int p = p0 + lane; p < p1; p += 64) {
      int c = col_csr[p];
      float4 sd = *(const float4*)&s_dst[(size_t)c * 4];
      sm.x += __expf(lrelu(ss.x + sd.x) - mx.x);
      sm.y += __expf(lrelu(ss.y + sd.y) - mx.y);
      sm.z += __expf(lrelu(ss.z + sd.z) - mx.z);
      sm.w += __expf(lrelu(ss.w + sd.w) - mx.w);
    }
#pragma unroll
    for (int m = 1; m < 64; m <<= 1) {
      sm.x += __shfl_xor(sm.x, m);
      sm.y += __shfl_xor(sm.y, m);
      sm.z += __shfl_xor(sm.z, m);
      sm.w += __shfl_xor(sm.w, m);
    }
    float4 rd = make_float4(1.f / sm.x, 1.f / sm.y, 1.f / sm.z, 1.f / sm.w);
    if (lane == 0) {
      *(float4*)&mx_out[(size_t)r * 4] = mx;
      *(float4*)&rden_out[(size_t)r * 4] = rd;
    }
    for (int p = p0 + lane; p < p1; p += 64) {
      int c = col_csr[p];
      float4 sd = *(const float4*)&s_dst[(size_t)c * 4];
      float4 ex;
      ex.x = __expf(lrelu(ss.x + sd.x) - mx.x);
      ex.y = __expf(lrelu(ss.y + sd.y) - mx.y);
      ex.z = __expf(lrelu(ss.z + sd.z) - mx.z);
      ex.w = __expf(lrelu(ss.w + sd.w) - mx.w);
      u16 q[4] = {f2b(ex.x * rd.x), f2b(ex.y * rd.y), f2b(ex.z * rd.z), f2b(ex.w * rd.w)};
      *(ushort4*)&an16[(size_t)p * 4] = *(ushort4*)q;
    }
  }
}

// ---- K7: alpha_norm in original edge order (coalesced writes, L2 gathers) ----
__global__ void k_alphaf(const int* __restrict__ rowi, const int* __restrict__ coli,
                         const float* __restrict__ s_src, const float* __restrict__ s_dst,
                         const float* __restrict__ mx, const float* __restrict__ rden,
                         float* __restrict__ alpha_out) {
  int e = blockIdx.x * 256 + threadIdx.x;
  if (e >= NEDGES) return;
  int r = rowi[e], c = coli[e];
  float4 ss = *(const float4*)&s_src[(size_t)r * 4];
  float4 sd = *(const float4*)&s_dst[(size_t)c * 4];
  float4 m4 = *(const float4*)&mx[(size_t)r * 4];
  float4 rd = *(const float4*)&rden[(size_t)r * 4];
  float4 an;
  an.x = __expf(lrelu(ss.x + sd.x) - m4.x) * rd.x;
  an.y = __expf(lrelu(ss.y + sd.y) - m4.y) * rd.y;
  an.z = __expf(lrelu(ss.z + sd.z) - m4.z) * rd.z;
  an.w = __expf(lrelu(ss.w + sd.w) - m4.w) * rd.w;
  *(float4*)&alpha_out[(size_t)e * 4] = an;
}

// ---- K8: per-row wave aggregation, 8-deep gather pipeline, bf16 an ----
__global__ __launch_bounds__(256) void k_aggr(const int* __restrict__ col_csr,
                                              const int* __restrict__ row_ptr,
                                              const u16* __restrict__ an16,
                                              const u16* __restrict__ hb,
                                              float* __restrict__ out_mean) {
  const int wid = threadIdx.x >> 6;
  const int lane = threadIdx.x & 63;
  const int r = blockIdx.x * 4 + wid;
  if (r >= NNODES) return;
  const int p0 = row_ptr[r], p1 = row_ptr[r + 1];
  const int hd = lane >> 4;
  const int ch = lane << 1;
  float acc0 = 0.f, acc1 = 0.f;

  int p = p0;
  for (; p + 8 <= p1; p += 8) {
    int cs[8];
    float ws[8];
    u32 hv[8];
#pragma unroll
    for (int i = 0; i < 8; ++i) cs[i] = col_csr[p + i];
#pragma unroll
    for (int i = 0; i < 8; ++i) ws[i] = b2f(an16[(size_t)(p + i) * 4 + hd]);
#pragma unroll
    for (int i = 0; i < 8; ++i) hv[i] = *(const u32*)&hb[(size_t)cs[i] * HC + ch];
#pragma unroll
    for (int i = 0; i < 8; ++i) {
      acc0 += ws[i] * b2f((u16)(hv[i] & 0xFFFFu));
      acc1 += ws[i] * b2f((u16)(hv[i] >> 16));
    }
  }
  for (; p < p1; ++p) {
    int c = col_csr[p];
    float w = b2f(an16[(size_t)p * 4 + hd]);
    u32 hv = *(const u32*)&hb[(size_t)c * HC + ch];
    acc0 += w * b2f((u16)(hv & 0xFFFFu));
    acc1 += w * b2f((u16)(hv >> 16));
  }
  acc0 += __shfl_xor(acc0, 16);
  acc0 += __shfl_xor(acc0, 32);
  acc1 += __shfl_xor(acc1, 16);
  acc1 += __shfl_xor(acc1, 32);
  if (lane < 16) {
    float2 o = make_float2(acc0 * 0.25f, acc1 * 0.25f);
    *(float2*)&out_mean[(size_t)r * 32 + (lane << 1)] = o;
  }
}

extern "C" void kernel_launch(void* const* d_in, const int* in_sizes, int n_in,
                              void* d_out, int out_size, void* d_ws, size_t ws_size,
                              hipStream_t stream) {
  const float* x = (const float*)d_in[0];
  const int* ei = (const int*)d_in[1];
  const float* W = (const float*)d_in[2];
  const float* attn = (const float*)d_in[3];
  const int* rowi = ei;
  const int* coli = ei + NEDGES;

  float* out_mean = (float*)d_out;
  float* alpha_out = (float*)d_out + (size_t)NNODES * 32;

  char* w = (char*)d_ws;
  u16* hb = (u16*)w;          w += (size_t)NNODES * HC * 2;       // 12.8 MB
  u16* an16 = (u16*)w;        w += (size_t)NEDGES * 4 * 2;        // 12.8 MB
  float* s_src = (float*)w;   w += (size_t)NNODES * 4 * 4;        // 0.8 MB
  float* s_dst = (float*)w;   w += (size_t)NNODES * 4 * 4;
  float* mx = (float*)w;      w += (size_t)NNODES * 4 * 4;
  float* rden = (float*)w;    w += (size_t)NNODES * 4 * 4;
  int* counts = (int*)w;      w += (size_t)NNODES * 4;
  int* bsum = (int*)w;        w += (size_t)256 * 4;
  int* boff = (int*)w;        w += (size_t)256 * 4;
  int* row_ptr = (int*)w;     w += (size_t)50016 * 4;             // padded for alignment
  u16* lslot = (u16*)w;       w += (size_t)NEDGES * 2;            // 3.2 MB
  int* col_csr = (int*)w;     w += (size_t)NEDGES * 4;            // 6.4 MB
  u32* chunk_hist = (u32*)w;  w += (size_t)NCHUNK * WORDS * 4;    // 12.8 MB
  // total ~51.6 MB (< proven-working R3 footprint)

  k_gemm<<<(NNODES + 63) / 64, 256, 0, stream>>>(x, W, attn, hb, s_src, s_dst);
  k_chist<<<NCHUNK, 256, 0, stream>>>(rowi, chunk_hist, lslot);
  k_cscan<<<(WORDS + 63) / 64, 256, 0, stream>>>(chunk_hist, counts);
  k_scan1<<<NSB, 256, 0, stream>>>(counts, bsum);
  k_scan2<<<1, 256, 0, stream>>>(bsum, boff);
  k_scan3<<<NSB, 256, 0, stream>>>(counts, boff, row_ptr);
  k_scatter<<<(NEDGES + 255) / 256, 256, 0, stream>>>(rowi, coli, row_ptr, chunk_hist, lslot, col_csr);
  k_softmax<<<(NNODES + 3) / 4, 256, 0, stream>>>(col_csr, row_ptr, s_src, s_dst, mx, rden, an16);
  k_alphaf<<<(NEDGES + 255) / 256, 256, 0, stream>>>(rowi, coli, s_src, s_dst, mx, rden, alpha_out);
  k_aggr<<<(NNODES + 3) / 4, 256, 0, stream>>>(col_csr, row_ptr, an16, hb, out_mean);
}

// Round 5
// 231.431 us; speedup vs baseline: 5.1252x; 1.0772x over previous
//
#include <hip/hip_runtime.h>

#define NNODES 50000
#define NEDGES 1600000
#define IN_CH 256
#define HEADS 4
#define OUT_CH 32
#define HC 128                       // HEADS*OUT_CH
#define NSB ((NNODES + 255) / 256)   // 196 scan blocks
#define NCHUNK 128
#define CE 12500                     // edges per chunk; 128*12500 == NEDGES
#define WORDS 25000                  // u32 words per chunk hist (2 u16 bins/word)

typedef unsigned int u32;
typedef unsigned short u16;
typedef short bf16x8 __attribute__((ext_vector_type(8)));   // 8 bf16 in 4 VGPRs
typedef u16 u16x8 __attribute__((ext_vector_type(8)));
typedef float f32x4 __attribute__((ext_vector_type(4)));

__device__ __forceinline__ float b2f(u16 s) { return __uint_as_float(((u32)s) << 16); }
__device__ __forceinline__ u16 f2b(float f) {
  u32 u = __float_as_uint(f);
  u32 r = (u + 0x7FFFu + ((u >> 16) & 1u)) >> 16;
  return (u16)r;
}
__device__ __forceinline__ float lrelu(float v) { return v >= 0.f ? v : 0.2f * v; }

// ---- K0: W (256x128 f32) -> bf16, transposed+tiled: wt[((kt*128+n)*32+kk)] ----
__global__ __launch_bounds__(256) void k_wprep(const float* __restrict__ W,
                                               u16* __restrict__ wt) {
  int i = blockIdx.x * 256 + threadIdx.x;   // 0..32767
  if (i >= IN_CH * HC) return;
  int kk = i & 31;
  int n = (i >> 5) & 127;
  int kt = i >> 12;
  wt[i] = f2b(W[(size_t)(kt * 32 + kk) * HC + n]);
}

// ---- K1: h = x @ W via bf16 MFMA (x split hi+lo), fused bf16-h store + scores ----
__global__ __launch_bounds__(256) void k_gemm(const float* __restrict__ x,
                                              const u16* __restrict__ wt,
                                              const float* __restrict__ attn,
                                              u16* __restrict__ hb,
                                              float* __restrict__ s_src,
                                              float* __restrict__ s_dst) {
  __shared__ union {
    struct {
      u16 xh[64 * 32];    // 4 KB, XOR-swizzled
      u16 xl[64 * 32];    // 4 KB
      u16 wh[128 * 32];   // 8 KB
    } st;
    float cbuf[64 * 132]; // 33.8 KB (row stride 132 f32)
  } L;
  __shared__ float sA[256];
  const int tid = threadIdx.x;
  const int wave = tid >> 6;
  const int lane = tid & 63;
  const int row0 = blockIdx.x * 64;
  sA[tid] = attn[tid];

  f32x4 acc[4][2] = {};           // [mi 16-row frag][ni 16-col frag]
  const int frow = lane & 15;     // fragment row/col within 16
  const int koff = (lane >> 4) << 4;  // byte offset of 8-elem k-group

  // staging coords for x: each thread owns (r, kc*8)
  const int sr = tid >> 2;
  const int skc = (tid & 3) << 3;
  const int sgrow = row0 + sr;
  const int sxb = (sr << 6) + (skc << 1);
  const int sxs = sxb ^ ((sr & 7) << 4);

  for (int kt = 0; kt < 8; ++kt) {
    // stage x hi/lo (64 rows x 32 k)
    {
      float4 v0 = make_float4(0.f, 0.f, 0.f, 0.f), v1 = v0;
      if (sgrow < NNODES) {
        const float* px = &x[(size_t)sgrow * IN_CH + kt * 32 + skc];
        v0 = *(const float4*)px;
        v1 = *(const float4*)(px + 4);
      }
      float vv[8] = {v0.x, v0.y, v0.z, v0.w, v1.x, v1.y, v1.z, v1.w};
      u16x8 hi, lo;
#pragma unroll
      for (int i = 0; i < 8; ++i) {
        u16 h = f2b(vv[i]);
        hi[i] = h;
        lo[i] = f2b(vv[i] - b2f(h));
      }
      *(u16x8*)((char*)L.st.xh + sxs) = hi;
      *(u16x8*)((char*)L.st.xl + sxs) = lo;
    }
    // stage W tile (128 cols x 32 k), already bf16+transposed in global
#pragma unroll
    for (int li = 0; li < 2; ++li) {
      int i = tid + (li << 8);          // 0..511
      int col = i >> 2;
      int kb = (i & 3) << 4;
      u16x8 v = *(const u16x8*)((const char*)wt + (((size_t)(kt * 128 + col)) << 6) + kb);
      int sb = ((col << 6) + kb) ^ ((col & 7) << 4);
      *(u16x8*)((char*)L.st.wh + sb) = v;
    }
    __syncthreads();
    // MFMA: 4 m-frags x 2 n-frags, hi + lo products into same acc
    bf16x8 ah[4], al[4], bw[2];
#pragma unroll
    for (int mi = 0; mi < 4; ++mi) {
      int r = mi * 16 + frow;
      int sb = ((r << 6) + koff) ^ ((r & 7) << 4);
      ah[mi] = *(bf16x8*)((char*)L.st.xh + sb);
      al[mi] = *(bf16x8*)((char*)L.st.xl + sb);
    }
#pragma unroll
    for (int ni = 0; ni < 2; ++ni) {
      int c = (wave << 5) + ni * 16 + frow;
      int sb = ((c << 6) + koff) ^ ((c & 7) << 4);
      bw[ni] = *(bf16x8*)((char*)L.st.wh + sb);
    }
#pragma unroll
    for (int mi = 0; mi < 4; ++mi)
#pragma unroll
      for (int ni = 0; ni < 2; ++ni) {
        acc[mi][ni] = __builtin_amdgcn_mfma_f32_16x16x32_bf16(ah[mi], bw[ni], acc[mi][ni], 0, 0, 0);
        acc[mi][ni] = __builtin_amdgcn_mfma_f32_16x16x32_bf16(al[mi], bw[ni], acc[mi][ni], 0, 0, 0);
      }
    __syncthreads();
  }

  // dump acc -> LDS cbuf (C/D layout: col=lane&15, row=(lane>>4)*4+reg)
#pragma unroll
  for (int mi = 0; mi < 4; ++mi)
#pragma unroll
    for (int ni = 0; ni < 2; ++ni) {
#pragma unroll
      for (int reg = 0; reg < 4; ++reg) {
        int row = mi * 16 + ((lane >> 4) << 2) + reg;
        int col = (wave << 5) + (ni << 4) + frow;
        L.cbuf[row * 132 + col] = acc[mi][ni][reg];
      }
    }
  __syncthreads();

  // epilogue: bf16 h store + fused score partials (8-lane-group reduce per head)
  const int tc = tid & 31;
  const int tr = tid >> 5;
  const int head = tc >> 3;
  const int cb = (tc & 7) << 2;
  const float4 as4 = *(const float4*)&sA[head * 64 + cb];
  const float4 ad4 = *(const float4*)&sA[head * 64 + 32 + cb];
#pragma unroll
  for (int i = 0; i < 8; ++i) {
    int row = (tr << 3) + i;
    int grow = row0 + row;
    float4 v = *(const float4*)&L.cbuf[row * 132 + (tc << 2)];
    float ps = v.x * as4.x + v.y * as4.y + v.z * as4.z + v.w * as4.w;
    float pd = v.x * ad4.x + v.y * ad4.y + v.z * ad4.z + v.w * ad4.w;
    ps += __shfl_xor(ps, 1); ps += __shfl_xor(ps, 2); ps += __shfl_xor(ps, 4);
    pd += __shfl_xor(pd, 1); pd += __shfl_xor(pd, 2); pd += __shfl_xor(pd, 4);
    if (grow < NNODES) {
      u16 q[4] = {f2b(v.x), f2b(v.y), f2b(v.z), f2b(v.w)};
      *(ushort4*)&hb[(size_t)grow * HC + (tc << 2)] = *(ushort4*)q;
      if ((tc & 7) == 0) {
        s_src[(size_t)grow * 4 + head] = ps;
        s_dst[(size_t)grow * 4 + head] = pd;
      }
    }
  }
}

// ---- K2: chunked LDS histogram (u16-packed), per-edge local slot ----
__global__ __launch_bounds__(256) void k_chist(const int* __restrict__ rowi,
                                               u32* __restrict__ chunk_hist,
                                               u16* __restrict__ lslot) {
  __shared__ u32 lh[WORDS];  // 100 KB
  const int c = blockIdx.x;
  const int tid = threadIdx.x;
  for (int i = tid; i < WORDS; i += 256) lh[i] = 0;
  __syncthreads();
  const int base = c * CE;
  for (int i = tid; i < CE; i += 256) {
    int e = base + i;
    int r = rowi[e];
    u32 sh = (u32)(r & 1) << 4;
    u32 old = atomicAdd(&lh[r >> 1], 1u << sh);
    lslot[e] = (u16)((old >> sh) & 0xFFFFu);
  }
  __syncthreads();
  u32* dst = chunk_hist + (size_t)c * WORDS;
  for (int i = tid; i < WORDS; i += 256) dst[i] = lh[i];
}

// ---- K3: in-place column scan of chunk_hist over chunks; per-row totals ----
__global__ __launch_bounds__(256) void k_cscan(u32* __restrict__ chunk_hist,
                                               int* __restrict__ counts) {
  __shared__ u32 tile[NCHUNK][64];  // 32 KB
  const int w0 = blockIdx.x * 64;
  const int tid = threadIdx.x;
  for (int i = tid; i < NCHUNK * 64; i += 256) {
    int c = i >> 6, wl = i & 63;
    int w = w0 + wl;
    tile[c][wl] = (w < WORDS) ? chunk_hist[(size_t)c * WORDS + w] : 0u;
  }
  __syncthreads();
  if (tid < 64) {
    u32 slo = 0, shi = 0;
    for (int c = 0; c < NCHUNK; ++c) {
      u32 v = tile[c][tid];
      tile[c][tid] = slo | (shi << 16);
      slo += v & 0xFFFFu;
      shi += v >> 16;
    }
    int w = w0 + tid;
    if (w < WORDS) {
      int r = w << 1;
      if (r < NNODES) counts[r] = (int)slo;
      if (r + 1 < NNODES) counts[r + 1] = (int)shi;
    }
  }
  __syncthreads();
  for (int i = tid; i < NCHUNK * 64; i += 256) {
    int c = i >> 6, wl = i & 63;
    int w = w0 + wl;
    if (w < WORDS) chunk_hist[(size_t)c * WORDS + w] = tile[c][wl];
  }
}

// ---- K4a/b/c: full-GPU 3-phase exclusive scan of counts -> row_ptr ----
__global__ __launch_bounds__(256) void k_scan1(const int* __restrict__ counts,
                                               int* __restrict__ bsum) {
  int i = blockIdx.x * 256 + threadIdx.x;
  int v = (i < NNODES) ? counts[i] : 0;
#pragma unroll
  for (int m = 1; m < 64; m <<= 1) v += __shfl_xor(v, m);
  __shared__ int ws[4];
  if ((threadIdx.x & 63) == 0) ws[threadIdx.x >> 6] = v;
  __syncthreads();
  if (threadIdx.x == 0) bsum[blockIdx.x] = ws[0] + ws[1] + ws[2] + ws[3];
}

__global__ __launch_bounds__(256) void k_scan2(const int* __restrict__ bsum,
                                               int* __restrict__ boff) {
  __shared__ int s[256];
  int t = threadIdx.x;
  int v = (t < NSB) ? bsum[t] : 0;
  s[t] = v;
  __syncthreads();
  for (int off = 1; off < 256; off <<= 1) {
    int u = (t >= off) ? s[t - off] : 0;
    __syncthreads();
    s[t] += u;
    __syncthreads();
  }
  boff[t] = s[t] - v;
}

__global__ __launch_bounds__(256) void k_scan3(const int* __restrict__ counts,
                                               const int* __restrict__ boff,
                                               int* __restrict__ row_ptr) {
  __shared__ int s[256];
  int t = threadIdx.x;
  int i = blockIdx.x * 256 + t;
  int v = (i < NNODES) ? counts[i] : 0;
  s[t] = v;
  __syncthreads();
  for (int off = 1; off < 256; off <<= 1) {
    int u = (t >= off) ? s[t - off] : 0;
    __syncthreads();
    s[t] += u;
    __syncthreads();
  }
  if (i < NNODES) row_ptr[i] = boff[blockIdx.x] + s[t] - v;
  if (i == 0) row_ptr[NNODES] = NEDGES;
}

// ---- K5: atomic-free scatter of col into CSR ----
__global__ void k_scatter(const int* __restrict__ rowi, const int* __restrict__ coli,
                          const int* __restrict__ row_ptr,
                          const u32* __restrict__ chunk_hist,
                          const u16* __restrict__ lslot,
                          int* __restrict__ col_csr) {
  int e = blockIdx.x * 256 + threadIdx.x;
  if (e >= NEDGES) return;
  int r = rowi[e];
  int c = e / CE;
  u32 word = chunk_hist[(size_t)c * WORDS + (r >> 1)];
  int off = (int)((word >> ((u32)(r & 1) << 4)) & 0xFFFFu);
  int pos = row_ptr[r] + off + (int)lslot[e];
  col_csr[pos] = coli[e];
}

// ---- K6: per-row wave softmax: writes mx, rden + bf16 an in CSR order ----
__global__ __launch_bounds__(256) void k_softmax(const int* __restrict__ col_csr,
                                                 const int* __restrict__ row_ptr,
                                                 const float* __restrict__ s_src,
                                                 const float* __restrict__ s_dst,
                                                 float* __restrict__ mx_out,
                                                 float* __restrict__ rden_out,
                                                 u16* __restrict__ an16) {
  const int wid = threadIdx.x >> 6;
  const int lane = threadIdx.x & 63;
  const int r = blockIdx.x * 4 + wid;
  if (r >= NNODES) return;
  const int p0 = row_ptr[r], p1 = row_ptr[r + 1];
  const int deg = p1 - p0;
  if (deg == 0) return;
  const float4 ss = *(const float4*)&s_src[(size_t)r * 4];
  const float NEG = -3.0e38f;

  if (deg <= 64) {
    float4 al = make_float4(NEG, NEG, NEG, NEG);
    if (lane < deg) {
      int c = col_csr[p0 + lane];
      float4 sd = *(const float4*)&s_dst[(size_t)c * 4];
      al.x = lrelu(ss.x + sd.x);
      al.y = lrelu(ss.y + sd.y);
      al.z = lrelu(ss.z + sd.z);
      al.w = lrelu(ss.w + sd.w);
    }
    float4 mx = al;
#pragma unroll
    for (int m = 1; m < 64; m <<= 1) {
      mx.x = fmaxf(mx.x, __shfl_xor(mx.x, m));
      mx.y = fmaxf(mx.y, __shfl_xor(mx.y, m));
      mx.z = fmaxf(mx.z, __shfl_xor(mx.z, m));
      mx.w = fmaxf(mx.w, __shfl_xor(mx.w, m));
    }
    float4 ex = make_float4(0.f, 0.f, 0.f, 0.f);
    if (lane < deg) {
      ex.x = __expf(al.x - mx.x);
      ex.y = __expf(al.y - mx.y);
      ex.z = __expf(al.z - mx.z);
      ex.w = __expf(al.w - mx.w);
    }
    float4 sm = ex;
#pragma unroll
    for (int m = 1; m < 64; m <<= 1) {
      sm.x += __shfl_xor(sm.x, m);
      sm.y += __shfl_xor(sm.y, m);
      sm.z += __shfl_xor(sm.z, m);
      sm.w += __shfl_xor(sm.w, m);
    }
    float4 rd = make_float4(1.f / sm.x, 1.f / sm.y, 1.f / sm.z, 1.f / sm.w);
    if (lane == 0) {
      *(float4*)&mx_out[(size_t)r * 4] = mx;
      *(float4*)&rden_out[(size_t)r * 4] = rd;
    }
    if (lane < deg) {
      u16 q[4] = {f2b(ex.x * rd.x), f2b(ex.y * rd.y), f2b(ex.z * rd.z), f2b(ex.w * rd.w)};
      *(ushort4*)&an16[(size_t)(p0 + lane) * 4] = *(ushort4*)q;
    }
  } else {
    float4 mx = make_float4(NEG, NEG, NEG, NEG);
    for (int p = p0 + lane; p < p1; p += 64) {
      int c = col_csr[p];
      float4 sd = *(const float4*)&s_dst[(size_t)c * 4];
      mx.x = fmaxf(mx.x, lrelu(ss.x + sd.x));
      mx.y = fmaxf(mx.y, lrelu(ss.y + sd.y));
      mx.z = fmaxf(mx.z, lrelu(ss.z + sd.z));
      mx.w = fmaxf(mx.w, lrelu(ss.w + sd.w));
    }
#pragma unroll
    for (int m = 1; m < 64; m <<= 1) {
      mx.x = fmaxf(mx.x, __shfl_xor(mx.x, m));
      mx.y = fmaxf(mx.y, __shfl_xor(mx.y, m));
      mx.z = fmaxf(mx.z, __shfl_xor(mx.z, m));
      mx.w = fmaxf(mx.w, __shfl_xor(mx.w, m));
    }
    float4 sm = make_float4(0.f, 0.f, 0.f, 0.f);
    for (int p = p0 + lane; p < p1; p += 64) {
      int c = col_csr[p];
      float4 sd = *(const float4*)&s_dst[(size_t)c * 4];
      sm.x += __expf(lrelu(ss.x + sd.x) - mx.x);
      sm.y += __expf(lrelu(ss.y + sd.y) - mx.y);
      sm.z += __expf(lrelu(ss.z + sd.z) - mx.z);
      sm.w += __expf(lrelu(ss.w + sd.w) - mx.w);
    }
#pragma unroll
    for (int m = 1; m < 64; m <<= 1) {
      sm.x += __shfl_xor(sm.x, m);
      sm.y += __shfl_xor(sm.y, m);
      sm.z += __shfl_xor(sm.z, m);
      sm.w += __shfl_xor(sm.w, m);
    }
    float4 rd = make_float4(1.f / sm.x, 1.f / sm.y, 1.f / sm.z, 1.f / sm.w);
    if (lane == 0) {
      *(float4*)&mx_out[(size_t)r * 4] = mx;
      *(float4*)&rden_out[(size_t)r * 4] = rd;
    }
    for (int p = p0 + lane; p < p1; p += 64) {
      int c = col_csr[p];
      float4 sd = *(const float4*)&s_dst[(size_t)c * 4];
      float4 ex;
      ex.x = __expf(lrelu(ss.x + sd.x) - mx.x);
      ex.y = __expf(lrelu(ss.y + sd.y) - mx.y);
      ex.z = __expf(lrelu(ss.z + sd.z) - mx.z);
      ex.w = __expf(lrelu(ss.w + sd.w) - mx.w);
      u16 q[4] = {f2b(ex.x * rd.x), f2b(ex.y * rd.y), f2b(ex.z * rd.z), f2b(ex.w * rd.w)};
      *(ushort4*)&an16[(size_t)p * 4] = *(ushort4*)q;
    }
  }
}

// ---- K7: alpha_norm in original edge order (coalesced writes) ----
__global__ void k_alphaf(const int* __restrict__ rowi, const int* __restrict__ coli,
                         const float* __restrict__ s_src, const float* __restrict__ s_dst,
                         const float* __restrict__ mx, const float* __restrict__ rden,
                         float* __restrict__ alpha_out) {
  int e = blockIdx.x * 256 + threadIdx.x;
  if (e >= NEDGES) return;
  int r = rowi[e], c = coli[e];
  float4 ss = *(const float4*)&s_src[(size_t)r * 4];
  float4 sd = *(const float4*)&s_dst[(size_t)c * 4];
  float4 m4 = *(const float4*)&mx[(size_t)r * 4];
  float4 rd = *(const float4*)&rden[(size_t)r * 4];
  float4 an;
  an.x = __expf(lrelu(ss.x + sd.x) - m4.x) * rd.x;
  an.y = __expf(lrelu(ss.y + sd.y) - m4.y) * rd.y;
  an.z = __expf(lrelu(ss.z + sd.z) - m4.z) * rd.z;
  an.w = __expf(lrelu(ss.w + sd.w) - m4.w) * rd.w;
  *(float4*)&alpha_out[(size_t)e * 4] = an;
}

// ---- K8: per-row wave aggregation, 8-deep gather pipeline, bf16 an ----
__global__ __launch_bounds__(256) void k_aggr(const int* __restrict__ col_csr,
                                              const int* __restrict__ row_ptr,
                                              const u16* __restrict__ an16,
                                              const u16* __restrict__ hb,
                                              float* __restrict__ out_mean) {
  const int wid = threadIdx.x >> 6;
  const int lane = threadIdx.x & 63;
  const int r = blockIdx.x * 4 + wid;
  if (r >= NNODES) return;
  const int p0 = row_ptr[r], p1 = row_ptr[r + 1];
  const int hd = lane >> 4;
  const int ch = lane << 1;
  float acc0 = 0.f, acc1 = 0.f;

  int p = p0;
  for (; p + 8 <= p1; p += 8) {
    int cs[8];
    float ws[8];
    u32 hv[8];
#pragma unroll
    for (int i = 0; i < 8; ++i) cs[i] = col_csr[p + i];
#pragma unroll
    for (int i = 0; i < 8; ++i) ws[i] = b2f(an16[(size_t)(p + i) * 4 + hd]);
#pragma unroll
    for (int i = 0; i < 8; ++i) hv[i] = *(const u32*)&hb[(size_t)cs[i] * HC + ch];
#pragma unroll
    for (int i = 0; i < 8; ++i) {
      acc0 += ws[i] * b2f((u16)(hv[i] & 0xFFFFu));
      acc1 += ws[i] * b2f((u16)(hv[i] >> 16));
    }
  }
  for (; p < p1; ++p) {
    int c = col_csr[p];
    float w = b2f(an16[(size_t)p * 4 + hd]);
    u32 hv = *(const u32*)&hb[(size_t)c * HC + ch];
    acc0 += w * b2f((u16)(hv & 0xFFFFu));
    acc1 += w * b2f((u16)(hv >> 16));
  }
  acc0 += __shfl_xor(acc0, 16);
  acc0 += __shfl_xor(acc0, 32);
  acc1 += __shfl_xor(acc1, 16);
  acc1 += __shfl_xor(acc1, 32);
  if (lane < 16) {
    float2 o = make_float2(acc0 * 0.25f, acc1 * 0.25f);
    *(float2*)&out_mean[(size_t)r * 32 + (lane << 1)] = o;
  }
}

extern "C" void kernel_launch(void* const* d_in, const int* in_sizes, int n_in,
                              void* d_out, int out_size, void* d_ws, size_t ws_size,
                              hipStream_t stream) {
  const float* x = (const float*)d_in[0];
  const int* ei = (const int*)d_in[1];
  const float* W = (const float*)d_in[2];
  const float* attn = (const float*)d_in[3];
  const int* rowi = ei;
  const int* coli = ei + NEDGES;

  float* out_mean = (float*)d_out;
  float* alpha_out = (float*)d_out + (size_t)NNODES * 32;

  char* w = (char*)d_ws;
  u16* hb = (u16*)w;          w += (size_t)NNODES * HC * 2;       // 12.8 MB
  u16* an16 = (u16*)w;        w += (size_t)NEDGES * 4 * 2;        // 12.8 MB
  float* s_src = (float*)w;   w += (size_t)NNODES * 4 * 4;        // 0.8 MB
  float* s_dst = (float*)w;   w += (size_t)NNODES * 4 * 4;
  float* mx = (float*)w;      w += (size_t)NNODES * 4 * 4;
  float* rden = (float*)w;    w += (size_t)NNODES * 4 * 4;
  int* counts = (int*)w;      w += (size_t)NNODES * 4;
  int* bsum = (int*)w;        w += (size_t)256 * 4;
  int* boff = (int*)w;        w += (size_t)256 * 4;
  int* row_ptr = (int*)w;     w += (size_t)50016 * 4;
  u16* lslot = (u16*)w;       w += (size_t)NEDGES * 2;            // 3.2 MB
  int* col_csr = (int*)w;     w += (size_t)NEDGES * 4;            // 6.4 MB
  u32* chunk_hist = (u32*)w;  w += (size_t)NCHUNK * WORDS * 4;    // 12.8 MB
  u16* wt = (u16*)w;          w += (size_t)IN_CH * HC * 2;        // 64 KB

  k_wprep<<<(IN_CH * HC + 255) / 256, 256, 0, stream>>>(W, wt);
  k_gemm<<<(NNODES + 63) / 64, 256, 0, stream>>>(x, wt, attn, hb, s_src, s_dst);
  k_chist<<<NCHUNK, 256, 0, stream>>>(rowi, chunk_hist, lslot);
  k_cscan<<<(WORDS + 63) / 64, 256, 0, stream>>>(chunk_hist, counts);
  k_scan1<<<NSB, 256, 0, stream>>>(counts, bsum);
  k_scan2<<<1, 256, 0, stream>>>(bsum, boff);
  k_scan3<<<NSB, 256, 0, stream>>>(counts, boff, row_ptr);
  k_scatter<<<(NEDGES + 255) / 256, 256, 0, stream>>>(rowi, coli, row_ptr, chunk_hist, lslot, col_csr);
  k_softmax<<<(NNODES + 3) / 4, 256, 0, stream>>>(col_csr, row_ptr, s_src, s_dst, mx, rden, an16);
  k_alphaf<<<(NEDGES + 255) / 256, 256, 0, stream>>>(rowi, coli, s_src, s_dst, mx, rden, alpha_out);
  k_aggr<<<(NNODES + 3) / 4, 256, 0, stream>>>(col_csr, row_ptr, an16, hb, out_mean);
}